// Round 12
// baseline (332.744 us; speedup 1.0000x reference)
//
#include <hip/hip_runtime.h>
#include <math.h>

#define NN     50000
#define FF     256
#define HH     64
#define NHEADS 4
#define EE     800000
#define OUTD   16

typedef __attribute__((ext_vector_type(8))) short short8;
typedef __attribute__((ext_vector_type(4))) float f32x4;

__device__ inline unsigned short f2bf(float f) {
    unsigned u = __builtin_bit_cast(unsigned, f);
    unsigned r = (u + 0x7fff + ((u >> 16) & 1)) >> 16;
    return (unsigned short)r;
}
__device__ inline float bf2f(unsigned short s) {
    unsigned u = ((unsigned)s) << 16;
    return __builtin_bit_cast(float, u);
}

// ---------------------------------------------------------------------------
// CSR build. Round-9: k_count merged into the GEMM launch. Round-12: the
// 3-kernel scan chain (a/b/c) collapsed into ONE kernel — each block
// redundantly computes its cross-block prefix by summing all preceding
// cnt[] (L2-resident 200KB; worst block reads 200KB ~ 1.3us). Launch
// count 9 -> 7; accounting showed ~12us/launch of dispatch overhead
// dominating the small-kernel pool.
// ---------------------------------------------------------------------------
__device__ inline void pack_one(const float* __restrict__ W,
                                unsigned short* __restrict__ bhi,
                                unsigned short* __restrict__ blo,
                                int t_, int NT, int NTOT, int TOFF, int SRC_NC) {
    int lane = t_ & 63;
    int tile = (t_ >> 6) % NT;
    int kb = (t_ >> 6) / NT;
    int q = lane >> 4, c = lane & 15;
    size_t off = ((size_t)(kb * NTOT + TOFF + tile) * 64 + lane) * 8;
#pragma unroll
    for (int j = 0; j < 8; j++) {
        float w = W[(size_t)(kb * 32 + q * 8 + j) * SRC_NC + tile * 16 + c];
        unsigned short h = f2bf(w);
        bhi[off + j] = h;
        if (blo) blo[off + j] = f2bf(w - bf2f(h));
    }
}

#define NTT 20
// zero cnt + pack all four weights, one launch (independent work).
__global__ __launch_bounds__(256) void k_prep(const float* __restrict__ Wg1,
                                              const float* __restrict__ Wgat1,
                                              const float* __restrict__ Wg2,
                                              const float* __restrict__ Wgat2,
                                              unsigned short* __restrict__ bhiC,
                                              unsigned short* __restrict__ bhiG2,
                                              unsigned short* __restrict__ bloG2,
                                              unsigned short* __restrict__ bhiA2,
                                              unsigned short* __restrict__ bloA2,
                                              int* __restrict__ cnt) {
    int t = blockIdx.x * 256 + threadIdx.x;
    if (t < NN) cnt[t] = 0;
    if (t < 2048)        pack_one(Wg1,   bhiC,  nullptr, t,         4,  NTT, 0, 64);
    else if (t < 10240)  pack_one(Wgat1, bhiC,  nullptr, t - 2048,  16, NTT, 4, 256);
    else if (t < 10368)  pack_one(Wg2,   bhiG2, bloG2,   t - 10240, 1,  1,   0, 16);
    else if (t < 10880)  pack_one(Wgat2, bhiA2, bloA2,   t - 10368, 1,  1,   0, 16);
}

// ONE-kernel scan (round-12): per-block redundant prefix + local scan.
__global__ __launch_bounds__(256) void k_scan(const int* __restrict__ cnt,
                                              int* __restrict__ row_start,
                                              int* __restrict__ cursor,
                                              float* __restrict__ dinv, int n) {
    __shared__ int arr[256];
    __shared__ int wsum[4];
    int tid = threadIdx.x;
    int base = blockIdx.x * 256;
    int i = base + tid;
    // cross-block prefix: sum cnt[0..base-1] (cnt is 200KB, L2-resident)
    int pre = 0;
    for (int j = tid; j < base; j += 256) pre += cnt[j];
#pragma unroll
    for (int off = 32; off >= 1; off >>= 1) pre += __shfl_xor(pre, off, 64);
    int wave = tid >> 6;
    if ((tid & 63) == 0) wsum[wave] = pre;
    int c = (i < n) ? cnt[i] : 0;
    arr[tid] = c;
    __syncthreads();
    int prefix = wsum[0] + wsum[1] + wsum[2] + wsum[3];
    // local inclusive scan
#pragma unroll
    for (int off = 1; off < 256; off <<= 1) {
        int v = arr[tid];
        int add = (tid >= off) ? arr[tid - off] : 0;
        __syncthreads();
        arr[tid] = v + add;
        __syncthreads();
    }
    if (i < n) {
        int excl = arr[tid] - c + prefix;
        row_start[i] = excl;
        cursor[i] = excl;
        dinv[i] = rsqrtf((float)(c + 1));
    }
    if (i == 0) row_start[n] = EE;   // total is statically EE
}

// k_fill + h1 dinv-scale, one launch (independent block ranges).
__global__ __launch_bounds__(256) void fill_scale(const int* __restrict__ src,
                                                  const int* __restrict__ dst,
                                                  int* __restrict__ cursor,
                                                  int* __restrict__ col,
                                                  unsigned short* __restrict__ h1,
                                                  const float* __restrict__ dinv,
                                                  int FB) {
    int bx = blockIdx.x;
    if (bx < FB) {
        int i = bx * 256 + threadIdx.x;
        if (i < EE) {
            int d = dst[i];
            int pos = atomicAdd(&cursor[d], 1);
            col[pos] = src[i];
        }
    } else {
        int t = (bx - FB) * 256 + threadIdx.x;   // 8 bf16 per thread
        if (t < NN * HH / 8) {
            int r = t >> 3;
            float sc = dinv[r];
            short8 v = *(short8*)(h1 + (size_t)t * 8);
#pragma unroll
            for (int j = 0; j < 8; j++)
                v[j] = (short)f2bf(bf2f((unsigned short)v[j]) * sc);
            *(short8*)(h1 + (size_t)t * 8) = v;
        }
    }
}

// ---------------------------------------------------------------------------
// FUSED big GEMM (512-thr, 8 waves; waves 0-3 tiles 0-9, waves 4-7 tiles
// 10-19 of the same rows) + INTERLEAVED k_count blocks (round-11, neutral
// but harmless). B staged once per block into LDS via global_load_lds,
// double-buffered (round-7 win; m97-ceiling regime — pipeline untouched).
// ---------------------------------------------------------------------------
__global__ __launch_bounds__(512, 4) void gemm_count(const float* __restrict__ A,
                                                     const unsigned short* __restrict__ Bhi,
                                                     unsigned short* __restrict__ Ch1,
                                                     unsigned char* __restrict__ Chg,
                                                     float* __restrict__ scl,
                                                     const float* __restrict__ a_s,
                                                     const float* __restrict__ a_d,
                                                     float* __restrict__ ssrc,
                                                     float* __restrict__ sdst,
                                                     const int* __restrict__ e_dst,
                                                     int* __restrict__ cnt,
                                                     int M) {
    int bx = blockIdx.x;
    if (bx % 3 != 0) {
        // count block, interleaved among gemm blocks
        int cb = (bx / 3) * 2 + (bx % 3) - 1;
        int i = cb * 512 + threadIdx.x;
        if (i < EE) atomicAdd(&cnt[e_dst[i]], 1);
        return;
    }
    int bgem = bx / 3;
    const int K = 256;
    int tid = threadIdx.x;
    int w = tid >> 6, lane = tid & 63, q = lane >> 4, c = lane & 15;
    int rg = w & 3;          // row group within block (16 rows each)
    int half = w >> 2;       // tile half: 0 -> tiles 0..9, 1 -> tiles 10..19
    const int T0 = half * 10;
    int row_base = bgem * 64 + rg * 16;
    int ar = min(row_base + c, M - 1);
    const float* ap = A + (size_t)ar * K + q * 8;

    __shared__ unsigned short ldsB[2][NTT * 512];   // 2 x 20 KB

    auto stage = [&](int kb, int buf) {
        const char* srcb = (const char*)Bhi + (size_t)kb * (NTT * 1024);
#pragma unroll
        for (int cch = 0; cch < 3; cch++) {
            int ch = w + cch * 8;
            if (ch < NTT) {
                __builtin_amdgcn_global_load_lds(
                    (const unsigned int*)(srcb + ch * 1024 + lane * 16),
                    (unsigned int*)((char*)&ldsB[buf][0] + ch * 1024),
                    16, 0, 0);
            }
        }
    };

    f32x4 acc[10];
#pragma unroll
    for (int t = 0; t < 10; t++) acc[t] = (f32x4){0.f, 0.f, 0.f, 0.f};

    float av[8];
    *(float4*)(av)     = *(const float4*)(ap);
    *(float4*)(av + 4) = *(const float4*)(ap + 4);
    stage(0, 0);
    __syncthreads();

    int buf = 0;
#pragma unroll
    for (int kb = 0; kb < 8; kb++) {
        if (kb < 7) stage(kb + 1, buf ^ 1);
        short8 ahi, alo;
#pragma unroll
        for (int j = 0; j < 8; j++) {
            unsigned short h = f2bf(av[j]);
            ahi[j] = (short)h;
            alo[j] = (short)f2bf(av[j] - bf2f(h));
        }
        if (kb < 7) {
            *(float4*)(av)     = *(const float4*)(ap + (kb + 1) * 32);
            *(float4*)(av + 4) = *(const float4*)(ap + (kb + 1) * 32 + 4);
        }
        const char* bbase = (const char*)&ldsB[buf][0] + lane * 16;
#pragma unroll
        for (int lt = 0; lt < 10; lt++) {
            short8 b = *(const short8*)(bbase + (size_t)(T0 + lt) * 1024);
            acc[lt] = __builtin_amdgcn_mfma_f32_16x16x32_bf16(ahi, b, acc[lt], 0, 0, 0);
            acc[lt] = __builtin_amdgcn_mfma_f32_16x16x32_bf16(alo, b, acc[lt], 0, 0, 0);
        }
        __syncthreads();
        buf ^= 1;
    }

    __shared__ float s_ss[2][64][4];
    __shared__ float s_sd[2][64][4];
    __shared__ float s_mx[2][64];

#pragma unroll
    for (int i = 0; i < 4; i++) {
        int lr = rg * 16 + q * 4 + i;
        float ss[4] = {0.f, 0.f, 0.f, 0.f};
        float sd[4] = {0.f, 0.f, 0.f, 0.f};
        float m = 0.f;
#pragma unroll
        for (int lt = 0; lt < 10; lt++) {
            int gt = T0 + lt;
            if (gt >= 4) {
                int t = gt - 4;
                float v = acc[lt][i];
                ss[t >> 2] += v * a_s[t * 16 + c];
                sd[t >> 2] += v * a_d[t * 16 + c];
                m = fmaxf(m, fabsf(v));
            }
        }
#pragma unroll
        for (int h = 0; h < 4; h++) {
#pragma unroll
            for (int off = 1; off <= 8; off <<= 1) {
                ss[h] += __shfl_xor(ss[h], off, 16);
                sd[h] += __shfl_xor(sd[h], off, 16);
            }
        }
#pragma unroll
        for (int off = 1; off <= 8; off <<= 1) m = fmaxf(m, __shfl_xor(m, off, 16));
        if (c == i) {
#pragma unroll
            for (int h = 0; h < 4; h++) {
                s_ss[half][lr][h] = ss[h];
                s_sd[half][lr][h] = sd[h];
            }
            s_mx[half][lr] = m;
        }
    }
    __syncthreads();

#pragma unroll
    for (int i = 0; i < 4; i++) {
        int lr = rg * 16 + q * 4 + i;
        int r = row_base + q * 4 + i;
        float m = fmaxf(fmaxf(s_mx[0][lr], s_mx[1][lr]), 1e-20f);
        float inv = 127.0f / m;
        if (half == 0 && c == i && r < M) {
            *(float4*)(ssrc + (size_t)r * 4) =
                make_float4(s_ss[0][lr][0] + s_ss[1][lr][0], s_ss[0][lr][1] + s_ss[1][lr][1],
                            s_ss[0][lr][2] + s_ss[1][lr][2], s_ss[0][lr][3] + s_ss[1][lr][3]);
            *(float4*)(sdst + (size_t)r * 4) =
                make_float4(s_sd[0][lr][0] + s_sd[1][lr][0], s_sd[0][lr][1] + s_sd[1][lr][1],
                            s_sd[0][lr][2] + s_sd[1][lr][2], s_sd[0][lr][3] + s_sd[1][lr][3]);
            scl[r] = m * (1.0f / 127.0f);
        }
        if (r < M) {
            if (half == 0) {
#pragma unroll
                for (int lt = 0; lt < 4; lt++)
                    Ch1[(size_t)r * 64 + lt * 16 + c] = f2bf(acc[lt][i]);  // unscaled
            }
#pragma unroll
            for (int lt = 0; lt < 10; lt++) {
                int gt = T0 + lt;
                if (gt >= 4) {
                    int t = gt - 4;
                    int qv = (int)rintf(acc[lt][i] * inv) + 128;
                    Chg[(size_t)r * 256 + t * 16 + c] = (unsigned char)qv;
                }
            }
        }
    }
}

// ---------------------------------------------------------------------------
// N=16 MFMA GEMM body; both small GEMMs in one launch (block-range split).
// ---------------------------------------------------------------------------
template <int KB, bool SCALE, bool SC2, int OFS>
__device__ inline void n16_body(int bx, int tid,
                                const unsigned short* __restrict__ A,
                                const unsigned short* __restrict__ Bhi,
                                const unsigned short* __restrict__ Blo,
                                unsigned short* __restrict__ Cbf,
                                const float* __restrict__ rowscale,
                                const float* __restrict__ a_s2,
                                const float* __restrict__ a_d2,
                                float* __restrict__ s2s,
                                float* __restrict__ s2d, int M) {
    const int K = KB * 32;
    int w = tid >> 6, lane = tid & 63, q = lane >> 4, c = lane & 15;
    int row_base = bx * 64 + w * 16;
    int ar = min(row_base + c, M - 1);
    const unsigned short* ap = A + (size_t)ar * K + q * 8;
    f32x4 acc = (f32x4){0.f, 0.f, 0.f, 0.f};
#pragma unroll
    for (int kb = 0; kb < KB; kb++) {
        short8 av = *(const short8*)(ap + kb * 32);
        size_t bo = ((size_t)kb * 64 + lane) * 8;
        short8 bh = *(const short8*)(Bhi + bo);
        short8 bl = *(const short8*)(Blo + bo);
        acc = __builtin_amdgcn_mfma_f32_16x16x32_bf16(av, bh, acc, 0, 0, 0);
        acc = __builtin_amdgcn_mfma_f32_16x16x32_bf16(av, bl, acc, 0, 0, 0);
    }
    if (SC2) {
#pragma unroll
        for (int i = 0; i < 4; i++) {
            float ps = acc[i] * a_s2[c];
            float pd = acc[i] * a_d2[c];
#pragma unroll
            for (int off = 1; off <= 8; off <<= 1) {
                ps += __shfl_xor(ps, off, 16);
                pd += __shfl_xor(pd, off, 16);
            }
            int r = row_base + q * 4 + i;
            if (c == i && r < M) {
                s2s[r] = ps;
                s2d[r] = pd;
            }
        }
    }
#pragma unroll
    for (int i = 0; i < 4; i++) {
        int r = row_base + q * 4 + i;
        if (r < M) {
            float sc = SCALE ? rowscale[r] : 1.0f;
            Cbf[((size_t)r * 16 + c) * 2 + OFS] = f2bf(acc[i] * sc);
        }
    }
}

__global__ __launch_bounds__(256) void mfma_n16_both(const unsigned short* __restrict__ Ag,
                                                     const unsigned short* __restrict__ Ac,
                                                     const unsigned short* __restrict__ bhiA2,
                                                     const unsigned short* __restrict__ bloA2,
                                                     const unsigned short* __restrict__ bhiG2,
                                                     const unsigned short* __restrict__ bloG2,
                                                     unsigned short* __restrict__ pairb,
                                                     const float* __restrict__ dinv,
                                                     const float* __restrict__ a_s2,
                                                     const float* __restrict__ a_d2,
                                                     float* __restrict__ s2s,
                                                     float* __restrict__ s2d,
                                                     int M, int GB) {
    int bx = blockIdx.x;
    if (bx < GB)
        n16_body<8, false, true, 1>(bx, threadIdx.x, Ag, bhiA2, bloA2, pairb,
                                    nullptr, a_s2, a_d2, s2s, s2d, M);
    else
        n16_body<2, true, false, 0>(bx - GB, threadIdx.x, Ac, bhiG2, bloG2, pairb,
                                    dinv, nullptr, nullptr, nullptr, nullptr, M);
}

// ---------------------------------------------------------------------------
// FUSED layer-1 aggregation: GAT1 (LDS-staged p/src, UNROLL-4 gather) +
// GCN1 riding the same sl[]. GAT hidden gathered as biased int8
// (4 B/lane/edge); h1 bf16 (round-5: int8 h1 saved no HBM bytes).
// Round-8 lesson: fusing layer-2 projections here cost +52 us — reverted.
// ---------------------------------------------------------------------------
__global__ __launch_bounds__(256) void both_agg(const unsigned char* __restrict__ hg,
                                                const unsigned short* __restrict__ h1,
                                                const float* __restrict__ scl,
                                                const int* __restrict__ rs,
                                                const int* __restrict__ col,
                                                const float* __restrict__ ssrc,
                                                const float* __restrict__ sdst,
                                                const float* __restrict__ dinv,
                                                const float* __restrict__ bgat,
                                                const float* __restrict__ bgcn,
                                                unsigned short* __restrict__ outg,
                                                unsigned short* __restrict__ outc) {
    __shared__ int s_lds[4][64];
    __shared__ float p_lds[4][64 * 4];
    int tid = threadIdx.x;
    int w = tid >> 6, lane = tid & 63;
    int wid = blockIdx.x * 4 + w;       // grid exact: 12500*4 = NN
    int hh = lane >> 4;
    int cidx = (lane & 15) * 4;
    int* sl = s_lds[w];
    float* pl = p_lds[w];

    float di = dinv[wid];
    float4 sd4 = *(const float4*)(sdst + (size_t)wid * 4);
    float sdv[4] = {sd4.x, sd4.y, sd4.z, sd4.w};
    float4 sf4 = *(const float4*)(ssrc + (size_t)wid * 4);
    float sfv[4] = {sf4.x, sf4.y, sf4.z, sf4.w};
    float psf[4];
#pragma unroll
    for (int h = 0; h < 4; h++) {
        float e = sfv[h] + sdv[h];
        e = (e >= 0.f) ? e : 0.2f * e;
        psf[h] = __expf(e);
    }
    float pse = (hh & 2) ? ((hh & 1) ? psf[3] : psf[2]) : ((hh & 1) ? psf[1] : psf[0]);
    // self term: decode with explicit -128 (bias correction below covers edges only)
    float pses = pse * scl[wid];
    const unsigned char* hbase = hg + lane * 4;
    unsigned hv0 = *(const unsigned*)(hbase + (size_t)wid * 256);
    float4 acc;
    acc.x = ((float)(hv0 & 0xffu) - 128.f) * pses;
    acc.y = ((float)((hv0 >> 8) & 0xffu) - 128.f) * pses;
    acc.z = ((float)((hv0 >> 16) & 0xffu) - 128.f) * pses;
    acc.w = ((float)(hv0 >> 24) - 128.f) * pses;
    float accb = 0.f;   // sum of p*s over edges (for -128 bias correction)
    float4 accc = make_float4(0.f, 0.f, 0.f, 0.f);

    float lsum[4] = {0.f, 0.f, 0.f, 0.f};
    int beg = rs[wid], end = rs[wid + 1];
    for (int j0 = beg; j0 < end; j0 += 64) {
        int cnt = min(64, end - j0);
        if (lane < cnt) {
            int sreg = col[j0 + lane];
            float ssc = scl[sreg];
            float4 sv = *(const float4*)(ssrc + (size_t)sreg * 4);
            float svv[4] = {sv.x, sv.y, sv.z, sv.w};
            float pv[4];
#pragma unroll
            for (int h = 0; h < 4; h++) {
                float e = svv[h] + sdv[h];
                e = (e >= 0.f) ? e : 0.2f * e;
                pv[h] = __expf(e);
                lsum[h] += pv[h];
            }
            sl[lane] = sreg;
            *(float4*)&pl[lane * 4] =
                make_float4(pv[0] * ssc, pv[1] * ssc, pv[2] * ssc, pv[3] * ssc);
        }
        // same-wave LDS write->read: DS pipe in-order per wave, no barrier
        int e = 0;
        for (; e + 4 <= cnt; e += 4) {
            int s0 = sl[e], s1 = sl[e + 1], s2 = sl[e + 2], s3 = sl[e + 3];
            float p0 = pl[e * 4 + hh], p1 = pl[(e + 1) * 4 + hh];
            float p2 = pl[(e + 2) * 4 + hh], p3 = pl[(e + 3) * 4 + hh];
            unsigned v0 = *(const unsigned*)(hbase + (size_t)s0 * 256);
            unsigned v1 = *(const unsigned*)(hbase + (size_t)s1 * 256);
            unsigned v2 = *(const unsigned*)(hbase + (size_t)s2 * 256);
            unsigned v3 = *(const unsigned*)(hbase + (size_t)s3 * 256);
            acc.x += (float)(v0 & 0xffu) * p0;
            acc.y += (float)((v0 >> 8) & 0xffu) * p0;
            acc.z += (float)((v0 >> 16) & 0xffu) * p0;
            acc.w += (float)(v0 >> 24) * p0;
            acc.x += (float)(v1 & 0xffu) * p1;
            acc.y += (float)((v1 >> 8) & 0xffu) * p1;
            acc.z += (float)((v1 >> 16) & 0xffu) * p1;
            acc.w += (float)(v1 >> 24) * p1;
            acc.x += (float)(v2 & 0xffu) * p2;
            acc.y += (float)((v2 >> 8) & 0xffu) * p2;
            acc.z += (float)((v2 >> 16) & 0xffu) * p2;
            acc.w += (float)(v2 >> 24) * p2;
            acc.x += (float)(v3 & 0xffu) * p3;
            acc.y += (float)((v3 >> 8) & 0xffu) * p3;
            acc.z += (float)((v3 >> 16) & 0xffu) * p3;
            acc.w += (float)(v3 >> 24) * p3;
            accb += (p0 + p1) + (p2 + p3);
        }
        for (; e < cnt; e++) {
            int s = sl[e];
            float p = pl[e * 4 + hh];
            unsigned v = *(const unsigned*)(hbase + (size_t)s * 256);
            acc.x += (float)(v & 0xffu) * p;
            acc.y += (float)((v >> 8) & 0xffu) * p;
            acc.z += (float)((v >> 16) & 0xffu) * p;
            acc.w += (float)(v >> 24) * p;
            accb += p;
        }
        // GCN gather: group hh handles edges {hh, hh+4, ...}, 2 in flight
        int e2 = hh;
        for (; e2 + 4 < cnt; e2 += 8) {
            int sa = sl[e2], sb = sl[e2 + 4];
            ushort4 va = *(const ushort4*)(h1 + (size_t)sa * HH + cidx);
            ushort4 vb = *(const ushort4*)(h1 + (size_t)sb * HH + cidx);
            accc.x += bf2f(va.x) + bf2f(vb.x);
            accc.y += bf2f(va.y) + bf2f(vb.y);
            accc.z += bf2f(va.z) + bf2f(vb.z);
            accc.w += bf2f(va.w) + bf2f(vb.w);
        }
        if (e2 < cnt) {
            int sa = sl[e2];
            ushort4 va = *(const ushort4*)(h1 + (size_t)sa * HH + cidx);
            accc.x += bf2f(va.x); accc.y += bf2f(va.y);
            accc.z += bf2f(va.z); accc.w += bf2f(va.w);
        }
    }
    // int8 bias correction: subtract 128 * sum(p*s) once
    float corr = 128.0f * accb;
    acc.x -= corr; acc.y -= corr; acc.z -= corr; acc.w -= corr;
    // GAT epilogue
#pragma unroll
    for (int h = 0; h < 4; h++) {
        float v = lsum[h];
        for (int off = 32; off >= 1; off >>= 1) v += __shfl_xor(v, off, 64);
        lsum[h] = v + psf[h];
    }
    float lt = (hh & 2) ? ((hh & 1) ? lsum[3] : lsum[2]) : ((hh & 1) ? lsum[1] : lsum[0]);
    float li = 1.0f / lt;
    float4 bv = *(const float4*)(bgat + lane * 4);
    ushort4 o;
    o.x = f2bf(fmaxf(acc.x * li + bv.x, 0.f));
    o.y = f2bf(fmaxf(acc.y * li + bv.y, 0.f));
    o.z = f2bf(fmaxf(acc.z * li + bv.z, 0.f));
    o.w = f2bf(fmaxf(acc.w * li + bv.w, 0.f));
    *(ushort4*)(outg + (size_t)wid * 256 + lane * 4) = o;
    // GCN epilogue
#pragma unroll
    for (int off = 16; off <= 32; off <<= 1) {
        accc.x += __shfl_xor(accc.x, off, 64);
        accc.y += __shfl_xor(accc.y, off, 64);
        accc.z += __shfl_xor(accc.z, off, 64);
        accc.w += __shfl_xor(accc.w, off, 64);
    }
    if (hh == 0) {
        ushort4 sv = *(const ushort4*)(h1 + (size_t)wid * HH + cidx);
        float4 bc = *(const float4*)(bgcn + cidx);
        ushort4 oc;
        oc.x = f2bf(fmaxf((accc.x + bf2f(sv.x)) * di + bc.x, 0.f));
        oc.y = f2bf(fmaxf((accc.y + bf2f(sv.y)) * di + bc.y, 0.f));
        oc.z = f2bf(fmaxf((accc.z + bf2f(sv.z)) * di + bc.z, 0.f));
        oc.w = f2bf(fmaxf((accc.w + bf2f(sv.w)) * di + bc.w, 0.f));
        *(ushort4*)(outc + (size_t)wid * HH + cidx) = oc;
    }
}

// ---------------------------------------------------------------------------
// Final aggregation: fused GCN2 + GAT2 over the interleaved pair buffer.
// ---------------------------------------------------------------------------
__global__ __launch_bounds__(256) void final_agg(const unsigned* __restrict__ hp,
                                                 const int* __restrict__ rs,
                                                 const int* __restrict__ col,
                                                 const float* __restrict__ dinv,
                                                 const float* __restrict__ s2s,
                                                 const float* __restrict__ s2d,
                                                 const float* __restrict__ bg2,
                                                 const float* __restrict__ bga2,
                                                 float* __restrict__ out) {
    int t = blockIdx.x * 256 + threadIdx.x;
    int node = t >> 4;
    int c = t & 15;
    float di = dinv[node];
    float sd = s2d[node];
    float es = s2s[node] + sd;
    es = (es >= 0.f) ? es : 0.2f * es;
    float psf = __expf(es);
    unsigned pvs = hp[(size_t)node * 16 + c];
    float accg = bf2f((unsigned short)pvs);
    float acca = bf2f((unsigned short)(pvs >> 16)) * psf;
    float lp = 0.f;
    int beg = rs[node], end = rs[node + 1];
    for (int j0 = beg; j0 < end; j0 += 16) {
        int cnt = min(16, end - j0);
        int sreg = 0;
        float pr = 0.f;
        if (c < cnt) {
            sreg = col[j0 + c];
            float e = s2s[sreg] + sd;
            e = (e >= 0.f) ? e : 0.2f * e;
            pr = __expf(e);
            lp += pr;
        }
        for (int e = 0; e < cnt; e += 4) {
            int si[4];
            float pi[4];
#pragma unroll
            for (int u = 0; u < 4; u++) {
                si[u] = __shfl(sreg, (e + u) & 15, 16);
                pi[u] = __shfl(pr, (e + u) & 15, 16);
            }
            unsigned hv[4];
#pragma unroll
            for (int u = 0; u < 4; u++) hv[u] = hp[(size_t)si[u] * 16 + c];
#pragma unroll
            for (int u = 0; u < 4; u++) {
                if (e + u < cnt) {
                    accg += bf2f((unsigned short)hv[u]);
                    acca += bf2f((unsigned short)(hv[u] >> 16)) * pi[u];
                }
            }
        }
    }
    for (int off = 8; off >= 1; off >>= 1) lp += __shfl_xor(lp, off, 16);
    float l = lp + psf;
    out[(size_t)node * 32 + c] = accg * di + bg2[c];
    out[(size_t)node * 32 + 16 + c] = acca / l + bga2[c];
}

// ---------------------------------------------------------------------------
// Launch
// ---------------------------------------------------------------------------
extern "C" void kernel_launch(void* const* d_in, const int* in_sizes, int n_in,
                              void* d_out, int out_size, void* d_ws, size_t ws_size,
                              hipStream_t stream) {
    const float* x      = (const float*)d_in[0];
    const int*   ei     = (const int*)d_in[1];
    const float* Wg1    = (const float*)d_in[2];
    const float* bg1    = (const float*)d_in[3];
    const float* Wg2    = (const float*)d_in[4];
    const float* bg2    = (const float*)d_in[5];
    const float* Wgat1  = (const float*)d_in[6];
    const float* a_src1 = (const float*)d_in[7];
    const float* a_dst1 = (const float*)d_in[8];
    const float* bgat1  = (const float*)d_in[9];
    const float* Wgat2  = (const float*)d_in[10];
    const float* a_src2 = (const float*)d_in[11];
    const float* a_dst2 = (const float*)d_in[12];
    const float* bgat2  = (const float*)d_in[13];
    float* out = (float*)d_out;

    const int* e_src = ei;
    const int* e_dst = ei + EE;

    char* wsb = (char*)d_ws;
    size_t o = 0;
    auto alloc = [&](size_t bytes) -> void* {
        void* p = wsb + o;
        o += (bytes + 255) & ~(size_t)255;
        return p;
    };
    float* dinv            = (float*)alloc(NN * 4);
    float* ssrc1           = (float*)alloc((size_t)NN * 16);
    float* sdst1           = (float*)alloc((size_t)NN * 16);
    unsigned short* h1b    = (unsigned short*)alloc((size_t)NN * HH * 2);
    unsigned short* xg1    = (unsigned short*)alloc((size_t)NN * HH * 2);
    unsigned char*  hgb    = (unsigned char*)alloc((size_t)NN * 256);   // int8
    float* sclb            = (float*)alloc(NN * 4);                      // per-row scale
    unsigned short* xgat1  = (unsigned short*)alloc((size_t)NN * 256 * 2);
    unsigned short* pairb  = (unsigned short*)alloc((size_t)NN * 16 * 4);
    float* s2src           = (float*)alloc(NN * 4);
    float* s2dst           = (float*)alloc(NN * 4);
    unsigned short* bhiC   = (unsigned short*)alloc((size_t)8 * NTT * 512 * 2);
    unsigned short* bhiG2  = (unsigned short*)alloc(64 * 16 * 2);
    unsigned short* bloG2  = (unsigned short*)alloc(64 * 16 * 2);
    unsigned short* bhiA2  = (unsigned short*)alloc(256 * 16 * 2);
    unsigned short* bloA2  = (unsigned short*)alloc(256 * 16 * 2);
    int* cnt               = (int*)alloc(NN * 4);
    int* rowstart          = (int*)alloc((NN + 1) * 4);
    int* cursor            = (int*)alloc(NN * 4);
    int* colarr            = (int*)alloc((size_t)EE * 4);

    const int TB = 256;
    const int NB = (NN + 255) / 256;
    const int GB = (NN + 63) / 64;    // 782 gemm blocks
    const int FB = (EE + 255) / 256;  // 3125 fill blocks
    const int SB = (NN * HH / 8 + 255) / 256;  // 1563 h1-scale blocks
    const int G16 = (NN * 16) / 256;  // 3125

    // weight packing + cnt zeroing
    k_prep<<<NB, TB, 0, stream>>>(Wg1, Wgat1, Wg2, Wgat2,
                                  bhiC, bhiG2, bloG2, bhiA2, bloA2, cnt);
    // big GEMM (h1 unscaled) with edge-count blocks interleaved 1:2
    gemm_count<<<3 * GB, 512, 0, stream>>>(x, bhiC, h1b, hgb, sclb,
                                           a_src1, a_dst1, ssrc1, sdst1,
                                           e_dst, cnt, NN);
    // single-kernel scan (round-12: was 3 launches)
    k_scan<<<NB, TB, 0, stream>>>(cnt, rowstart, cursor, dinv, NN);
    // CSR fill + h1 dinv-scaling, one launch
    fill_scale<<<FB + SB, TB, 0, stream>>>(e_src, e_dst, cursor, colarr,
                                           h1b, dinv, FB);

    both_agg<<<NN / 4, TB, 0, stream>>>(hgb, h1b, sclb, rowstart, colarr, ssrc1, sdst1,
                                        dinv, bgat1, bg1, xgat1, xg1);

    mfma_n16_both<<<2 * GB, TB, 0, stream>>>(xgat1, xg1, bhiA2, bloA2, bhiG2, bloG2,
                                             pairb, dinv, a_src2, a_dst2,
                                             s2src, s2dst, NN, GB);

    final_agg<<<G16, TB, 0, stream>>>((const unsigned*)pairb, rowstart, colarr, dinv,
                                      s2src, s2dst, bg2, bgat2, out);
}

// Round 13
// 329.609 us; speedup vs baseline: 1.0095x; 1.0095x over previous
//
#include <hip/hip_runtime.h>
#include <math.h>

#define NN     50000
#define FF     256
#define HH     64
#define NHEADS 4
#define EE     800000
#define OUTD   16

typedef __attribute__((ext_vector_type(8))) short short8;
typedef __attribute__((ext_vector_type(4))) float f32x4;

__device__ inline unsigned short f2bf(float f) {
    unsigned u = __builtin_bit_cast(unsigned, f);
    unsigned r = (u + 0x7fff + ((u >> 16) & 1)) >> 16;
    return (unsigned short)r;
}
__device__ inline float bf2f(unsigned short s) {
    unsigned u = ((unsigned)s) << 16;
    return __builtin_bit_cast(float, u);
}

// ---------------------------------------------------------------------------
// CSR build. Round-9: k_count merged into the GEMM launch. Round-12: scan
// collapsed to ONE kernel (redundant per-block prefix over L2-resident
// cnt). Round-13: col[] stored as uint16 (NN=50000 < 2^16) — halves the
// fill scatter line-churn and the col stream in both_agg/final_agg.
// ---------------------------------------------------------------------------
__device__ inline void pack_one(const float* __restrict__ W,
                                unsigned short* __restrict__ bhi,
                                unsigned short* __restrict__ blo,
                                int t_, int NT, int NTOT, int TOFF, int SRC_NC) {
    int lane = t_ & 63;
    int tile = (t_ >> 6) % NT;
    int kb = (t_ >> 6) / NT;
    int q = lane >> 4, c = lane & 15;
    size_t off = ((size_t)(kb * NTOT + TOFF + tile) * 64 + lane) * 8;
#pragma unroll
    for (int j = 0; j < 8; j++) {
        float w = W[(size_t)(kb * 32 + q * 8 + j) * SRC_NC + tile * 16 + c];
        unsigned short h = f2bf(w);
        bhi[off + j] = h;
        if (blo) blo[off + j] = f2bf(w - bf2f(h));
    }
}

#define NTT 20
// zero cnt + pack all four weights, one launch (independent work).
__global__ __launch_bounds__(256) void k_prep(const float* __restrict__ Wg1,
                                              const float* __restrict__ Wgat1,
                                              const float* __restrict__ Wg2,
                                              const float* __restrict__ Wgat2,
                                              unsigned short* __restrict__ bhiC,
                                              unsigned short* __restrict__ bhiG2,
                                              unsigned short* __restrict__ bloG2,
                                              unsigned short* __restrict__ bhiA2,
                                              unsigned short* __restrict__ bloA2,
                                              int* __restrict__ cnt) {
    int t = blockIdx.x * 256 + threadIdx.x;
    if (t < NN) cnt[t] = 0;
    if (t < 2048)        pack_one(Wg1,   bhiC,  nullptr, t,         4,  NTT, 0, 64);
    else if (t < 10240)  pack_one(Wgat1, bhiC,  nullptr, t - 2048,  16, NTT, 4, 256);
    else if (t < 10368)  pack_one(Wg2,   bhiG2, bloG2,   t - 10240, 1,  1,   0, 16);
    else if (t < 10880)  pack_one(Wgat2, bhiA2, bloA2,   t - 10368, 1,  1,   0, 16);
}

// ONE-kernel scan (round-12): per-block redundant prefix + local scan.
__global__ __launch_bounds__(256) void k_scan(const int* __restrict__ cnt,
                                              int* __restrict__ row_start,
                                              int* __restrict__ cursor,
                                              float* __restrict__ dinv, int n) {
    __shared__ int arr[256];
    __shared__ int wsum[4];
    int tid = threadIdx.x;
    int base = blockIdx.x * 256;
    int i = base + tid;
    // cross-block prefix: sum cnt[0..base-1] (cnt is 200KB, L2-resident)
    int pre = 0;
    for (int j = tid; j < base; j += 256) pre += cnt[j];
#pragma unroll
    for (int off = 32; off >= 1; off >>= 1) pre += __shfl_xor(pre, off, 64);
    int wave = tid >> 6;
    if ((tid & 63) == 0) wsum[wave] = pre;
    int c = (i < n) ? cnt[i] : 0;
    arr[tid] = c;
    __syncthreads();
    int prefix = wsum[0] + wsum[1] + wsum[2] + wsum[3];
    // local inclusive scan
#pragma unroll
    for (int off = 1; off < 256; off <<= 1) {
        int v = arr[tid];
        int add = (tid >= off) ? arr[tid - off] : 0;
        __syncthreads();
        arr[tid] = v + add;
        __syncthreads();
    }
    if (i < n) {
        int excl = arr[tid] - c + prefix;
        row_start[i] = excl;
        cursor[i] = excl;
        dinv[i] = rsqrtf((float)(c + 1));
    }
    if (i == 0) row_start[n] = EE;   // total is statically EE
}

// k_fill + h1 dinv-scale, one launch (independent block ranges).
__global__ __launch_bounds__(256) void fill_scale(const int* __restrict__ src,
                                                  const int* __restrict__ dst,
                                                  int* __restrict__ cursor,
                                                  unsigned short* __restrict__ col,
                                                  unsigned short* __restrict__ h1,
                                                  const float* __restrict__ dinv,
                                                  int FB) {
    int bx = blockIdx.x;
    if (bx < FB) {
        int i = bx * 256 + threadIdx.x;
        if (i < EE) {
            int d = dst[i];
            int pos = atomicAdd(&cursor[d], 1);
            col[pos] = (unsigned short)src[i];
        }
    } else {
        int t = (bx - FB) * 256 + threadIdx.x;   // 8 bf16 per thread
        if (t < NN * HH / 8) {
            int r = t >> 3;
            float sc = dinv[r];
            short8 v = *(short8*)(h1 + (size_t)t * 8);
#pragma unroll
            for (int j = 0; j < 8; j++)
                v[j] = (short)f2bf(bf2f((unsigned short)v[j]) * sc);
            *(short8*)(h1 + (size_t)t * 8) = v;
        }
    }
}

// ---------------------------------------------------------------------------
// FUSED big GEMM (512-thr, 8 waves; waves 0-3 tiles 0-9, waves 4-7 tiles
// 10-19 of the same rows) + INTERLEAVED k_count blocks. B staged once per
// block into LDS via global_load_lds, double-buffered (round-7 win).
// Round-12 showed this kernel at ~92us with ALL rates scaled x0.8 and
// identical code/counters — clock-state variance, not a code effect.
// ---------------------------------------------------------------------------
__global__ __launch_bounds__(512, 4) void gemm_count(const float* __restrict__ A,
                                                     const unsigned short* __restrict__ Bhi,
                                                     unsigned short* __restrict__ Ch1,
                                                     unsigned char* __restrict__ Chg,
                                                     float* __restrict__ scl,
                                                     const float* __restrict__ a_s,
                                                     const float* __restrict__ a_d,
                                                     float* __restrict__ ssrc,
                                                     float* __restrict__ sdst,
                                                     const int* __restrict__ e_dst,
                                                     int* __restrict__ cnt,
                                                     int M) {
    int bx = blockIdx.x;
    if (bx % 3 != 0) {
        // count block, interleaved among gemm blocks
        int cb = (bx / 3) * 2 + (bx % 3) - 1;
        int i = cb * 512 + threadIdx.x;
        if (i < EE) atomicAdd(&cnt[e_dst[i]], 1);
        return;
    }
    int bgem = bx / 3;
    const int K = 256;
    int tid = threadIdx.x;
    int w = tid >> 6, lane = tid & 63, q = lane >> 4, c = lane & 15;
    int rg = w & 3;          // row group within block (16 rows each)
    int half = w >> 2;       // tile half: 0 -> tiles 0..9, 1 -> tiles 10..19
    const int T0 = half * 10;
    int row_base = bgem * 64 + rg * 16;
    int ar = min(row_base + c, M - 1);
    const float* ap = A + (size_t)ar * K + q * 8;

    __shared__ unsigned short ldsB[2][NTT * 512];   // 2 x 20 KB

    auto stage = [&](int kb, int buf) {
        const char* srcb = (const char*)Bhi + (size_t)kb * (NTT * 1024);
#pragma unroll
        for (int cch = 0; cch < 3; cch++) {
            int ch = w + cch * 8;
            if (ch < NTT) {
                __builtin_amdgcn_global_load_lds(
                    (const unsigned int*)(srcb + ch * 1024 + lane * 16),
                    (unsigned int*)((char*)&ldsB[buf][0] + ch * 1024),
                    16, 0, 0);
            }
        }
    };

    f32x4 acc[10];
#pragma unroll
    for (int t = 0; t < 10; t++) acc[t] = (f32x4){0.f, 0.f, 0.f, 0.f};

    float av[8];
    *(float4*)(av)     = *(const float4*)(ap);
    *(float4*)(av + 4) = *(const float4*)(ap + 4);
    stage(0, 0);
    __syncthreads();

    int buf = 0;
#pragma unroll
    for (int kb = 0; kb < 8; kb++) {
        if (kb < 7) stage(kb + 1, buf ^ 1);
        short8 ahi, alo;
#pragma unroll
        for (int j = 0; j < 8; j++) {
            unsigned short h = f2bf(av[j]);
            ahi[j] = (short)h;
            alo[j] = (short)f2bf(av[j] - bf2f(h));
        }
        if (kb < 7) {
            *(float4*)(av)     = *(const float4*)(ap + (kb + 1) * 32);
            *(float4*)(av + 4) = *(const float4*)(ap + (kb + 1) * 32 + 4);
        }
        const char* bbase = (const char*)&ldsB[buf][0] + lane * 16;
#pragma unroll
        for (int lt = 0; lt < 10; lt++) {
            short8 b = *(const short8*)(bbase + (size_t)(T0 + lt) * 1024);
            acc[lt] = __builtin_amdgcn_mfma_f32_16x16x32_bf16(ahi, b, acc[lt], 0, 0, 0);
            acc[lt] = __builtin_amdgcn_mfma_f32_16x16x32_bf16(alo, b, acc[lt], 0, 0, 0);
        }
        __syncthreads();
        buf ^= 1;
    }

    __shared__ float s_ss[2][64][4];
    __shared__ float s_sd[2][64][4];
    __shared__ float s_mx[2][64];

#pragma unroll
    for (int i = 0; i < 4; i++) {
        int lr = rg * 16 + q * 4 + i;
        float ss[4] = {0.f, 0.f, 0.f, 0.f};
        float sd[4] = {0.f, 0.f, 0.f, 0.f};
        float m = 0.f;
#pragma unroll
        for (int lt = 0; lt < 10; lt++) {
            int gt = T0 + lt;
            if (gt >= 4) {
                int t = gt - 4;
                float v = acc[lt][i];
                ss[t >> 2] += v * a_s[t * 16 + c];
                sd[t >> 2] += v * a_d[t * 16 + c];
                m = fmaxf(m, fabsf(v));
            }
        }
#pragma unroll
        for (int h = 0; h < 4; h++) {
#pragma unroll
            for (int off = 1; off <= 8; off <<= 1) {
                ss[h] += __shfl_xor(ss[h], off, 16);
                sd[h] += __shfl_xor(sd[h], off, 16);
            }
        }
#pragma unroll
        for (int off = 1; off <= 8; off <<= 1) m = fmaxf(m, __shfl_xor(m, off, 16));
        if (c == i) {
#pragma unroll
            for (int h = 0; h < 4; h++) {
                s_ss[half][lr][h] = ss[h];
                s_sd[half][lr][h] = sd[h];
            }
            s_mx[half][lr] = m;
        }
    }
    __syncthreads();

#pragma unroll
    for (int i = 0; i < 4; i++) {
        int lr = rg * 16 + q * 4 + i;
        int r = row_base + q * 4 + i;
        float m = fmaxf(fmaxf(s_mx[0][lr], s_mx[1][lr]), 1e-20f);
        float inv = 127.0f / m;
        if (half == 0 && c == i && r < M) {
            *(float4*)(ssrc + (size_t)r * 4) =
                make_float4(s_ss[0][lr][0] + s_ss[1][lr][0], s_ss[0][lr][1] + s_ss[1][lr][1],
                            s_ss[0][lr][2] + s_ss[1][lr][2], s_ss[0][lr][3] + s_ss[1][lr][3]);
            *(float4*)(sdst + (size_t)r * 4) =
                make_float4(s_sd[0][lr][0] + s_sd[1][lr][0], s_sd[0][lr][1] + s_sd[1][lr][1],
                            s_sd[0][lr][2] + s_sd[1][lr][2], s_sd[0][lr][3] + s_sd[1][lr][3]);
            scl[r] = m * (1.0f / 127.0f);
        }
        if (r < M) {
            if (half == 0) {
#pragma unroll
                for (int lt = 0; lt < 4; lt++)
                    Ch1[(size_t)r * 64 + lt * 16 + c] = f2bf(acc[lt][i]);  // unscaled
            }
#pragma unroll
            for (int lt = 0; lt < 10; lt++) {
                int gt = T0 + lt;
                if (gt >= 4) {
                    int t = gt - 4;
                    int qv = (int)rintf(acc[lt][i] * inv) + 128;
                    Chg[(size_t)r * 256 + t * 16 + c] = (unsigned char)qv;
                }
            }
        }
    }
}

// ---------------------------------------------------------------------------
// N=16 MFMA GEMM body; both small GEMMs in one launch (block-range split).
// ---------------------------------------------------------------------------
template <int KB, bool SCALE, bool SC2, int OFS>
__device__ inline void n16_body(int bx, int tid,
                                const unsigned short* __restrict__ A,
                                const unsigned short* __restrict__ Bhi,
                                const unsigned short* __restrict__ Blo,
                                unsigned short* __restrict__ Cbf,
                                const float* __restrict__ rowscale,
                                const float* __restrict__ a_s2,
                                const float* __restrict__ a_d2,
                                float* __restrict__ s2s,
                                float* __restrict__ s2d, int M) {
    const int K = KB * 32;
    int w = tid >> 6, lane = tid & 63, q = lane >> 4, c = lane & 15;
    int row_base = bx * 64 + w * 16;
    int ar = min(row_base + c, M - 1);
    const unsigned short* ap = A + (size_t)ar * K + q * 8;
    f32x4 acc = (f32x4){0.f, 0.f, 0.f, 0.f};
#pragma unroll
    for (int kb = 0; kb < KB; kb++) {
        short8 av = *(const short8*)(ap + kb * 32);
        size_t bo = ((size_t)kb * 64 + lane) * 8;
        short8 bh = *(const short8*)(Bhi + bo);
        short8 bl = *(const short8*)(Blo + bo);
        acc = __builtin_amdgcn_mfma_f32_16x16x32_bf16(av, bh, acc, 0, 0, 0);
        acc = __builtin_amdgcn_mfma_f32_16x16x32_bf16(av, bl, acc, 0, 0, 0);
    }
    if (SC2) {
#pragma unroll
        for (int i = 0; i < 4; i++) {
            float ps = acc[i] * a_s2[c];
            float pd = acc[i] * a_d2[c];
#pragma unroll
            for (int off = 1; off <= 8; off <<= 1) {
                ps += __shfl_xor(ps, off, 16);
                pd += __shfl_xor(pd, off, 16);
            }
            int r = row_base + q * 4 + i;
            if (c == i && r < M) {
                s2s[r] = ps;
                s2d[r] = pd;
            }
        }
    }
#pragma unroll
    for (int i = 0; i < 4; i++) {
        int r = row_base + q * 4 + i;
        if (r < M) {
            float sc = SCALE ? rowscale[r] : 1.0f;
            Cbf[((size_t)r * 16 + c) * 2 + OFS] = f2bf(acc[i] * sc);
        }
    }
}

__global__ __launch_bounds__(256) void mfma_n16_both(const unsigned short* __restrict__ Ag,
                                                     const unsigned short* __restrict__ Ac,
                                                     const unsigned short* __restrict__ bhiA2,
                                                     const unsigned short* __restrict__ bloA2,
                                                     const unsigned short* __restrict__ bhiG2,
                                                     const unsigned short* __restrict__ bloG2,
                                                     unsigned short* __restrict__ pairb,
                                                     const float* __restrict__ dinv,
                                                     const float* __restrict__ a_s2,
                                                     const float* __restrict__ a_d2,
                                                     float* __restrict__ s2s,
                                                     float* __restrict__ s2d,
                                                     int M, int GB) {
    int bx = blockIdx.x;
    if (bx < GB)
        n16_body<8, false, true, 1>(bx, threadIdx.x, Ag, bhiA2, bloA2, pairb,
                                    nullptr, a_s2, a_d2, s2s, s2d, M);
    else
        n16_body<2, true, false, 0>(bx - GB, threadIdx.x, Ac, bhiG2, bloG2, pairb,
                                    dinv, nullptr, nullptr, nullptr, nullptr, M);
}

// ---------------------------------------------------------------------------
// FUSED layer-1 aggregation: GAT1 (LDS-staged p/src, UNROLL-4 gather) +
// GCN1 riding the same sl[]. GAT hidden gathered as biased int8
// (4 B/lane/edge); h1 bf16. col now uint16 (round-13).
// ---------------------------------------------------------------------------
__global__ __launch_bounds__(256) void both_agg(const unsigned char* __restrict__ hg,
                                                const unsigned short* __restrict__ h1,
                                                const float* __restrict__ scl,
                                                const int* __restrict__ rs,
                                                const unsigned short* __restrict__ col,
                                                const float* __restrict__ ssrc,
                                                const float* __restrict__ sdst,
                                                const float* __restrict__ dinv,
                                                const float* __restrict__ bgat,
                                                const float* __restrict__ bgcn,
                                                unsigned short* __restrict__ outg,
                                                unsigned short* __restrict__ outc) {
    __shared__ int s_lds[4][64];
    __shared__ float p_lds[4][64 * 4];
    int tid = threadIdx.x;
    int w = tid >> 6, lane = tid & 63;
    int wid = blockIdx.x * 4 + w;       // grid exact: 12500*4 = NN
    int hh = lane >> 4;
    int cidx = (lane & 15) * 4;
    int* sl = s_lds[w];
    float* pl = p_lds[w];

    float di = dinv[wid];
    float4 sd4 = *(const float4*)(sdst + (size_t)wid * 4);
    float sdv[4] = {sd4.x, sd4.y, sd4.z, sd4.w};
    float4 sf4 = *(const float4*)(ssrc + (size_t)wid * 4);
    float sfv[4] = {sf4.x, sf4.y, sf4.z, sf4.w};
    float psf[4];
#pragma unroll
    for (int h = 0; h < 4; h++) {
        float e = sfv[h] + sdv[h];
        e = (e >= 0.f) ? e : 0.2f * e;
        psf[h] = __expf(e);
    }
    float pse = (hh & 2) ? ((hh & 1) ? psf[3] : psf[2]) : ((hh & 1) ? psf[1] : psf[0]);
    // self term: decode with explicit -128 (bias correction below covers edges only)
    float pses = pse * scl[wid];
    const unsigned char* hbase = hg + lane * 4;
    unsigned hv0 = *(const unsigned*)(hbase + (size_t)wid * 256);
    float4 acc;
    acc.x = ((float)(hv0 & 0xffu) - 128.f) * pses;
    acc.y = ((float)((hv0 >> 8) & 0xffu) - 128.f) * pses;
    acc.z = ((float)((hv0 >> 16) & 0xffu) - 128.f) * pses;
    acc.w = ((float)(hv0 >> 24) - 128.f) * pses;
    float accb = 0.f;   // sum of p*s over edges (for -128 bias correction)
    float4 accc = make_float4(0.f, 0.f, 0.f, 0.f);

    float lsum[4] = {0.f, 0.f, 0.f, 0.f};
    int beg = rs[wid], end = rs[wid + 1];
    for (int j0 = beg; j0 < end; j0 += 64) {
        int cnt = min(64, end - j0);
        if (lane < cnt) {
            int sreg = (int)col[j0 + lane];
            float ssc = scl[sreg];
            float4 sv = *(const float4*)(ssrc + (size_t)sreg * 4);
            float svv[4] = {sv.x, sv.y, sv.z, sv.w};
            float pv[4];
#pragma unroll
            for (int h = 0; h < 4; h++) {
                float e = svv[h] + sdv[h];
                e = (e >= 0.f) ? e : 0.2f * e;
                pv[h] = __expf(e);
                lsum[h] += pv[h];
            }
            sl[lane] = sreg;
            *(float4*)&pl[lane * 4] =
                make_float4(pv[0] * ssc, pv[1] * ssc, pv[2] * ssc, pv[3] * ssc);
        }
        // same-wave LDS write->read: DS pipe in-order per wave, no barrier
        int e = 0;
        for (; e + 4 <= cnt; e += 4) {
            int s0 = sl[e], s1 = sl[e + 1], s2 = sl[e + 2], s3 = sl[e + 3];
            float p0 = pl[e * 4 + hh], p1 = pl[(e + 1) * 4 + hh];
            float p2 = pl[(e + 2) * 4 + hh], p3 = pl[(e + 3) * 4 + hh];
            unsigned v0 = *(const unsigned*)(hbase + (size_t)s0 * 256);
            unsigned v1 = *(const unsigned*)(hbase + (size_t)s1 * 256);
            unsigned v2 = *(const unsigned*)(hbase + (size_t)s2 * 256);
            unsigned v3 = *(const unsigned*)(hbase + (size_t)s3 * 256);
            acc.x += (float)(v0 & 0xffu) * p0;
            acc.y += (float)((v0 >> 8) & 0xffu) * p0;
            acc.z += (float)((v0 >> 16) & 0xffu) * p0;
            acc.w += (float)(v0 >> 24) * p0;
            acc.x += (float)(v1 & 0xffu) * p1;
            acc.y += (float)((v1 >> 8) & 0xffu) * p1;
            acc.z += (float)((v1 >> 16) & 0xffu) * p1;
            acc.w += (float)(v1 >> 24) * p1;
            acc.x += (float)(v2 & 0xffu) * p2;
            acc.y += (float)((v2 >> 8) & 0xffu) * p2;
            acc.z += (float)((v2 >> 16) & 0xffu) * p2;
            acc.w += (float)(v2 >> 24) * p2;
            acc.x += (float)(v3 & 0xffu) * p3;
            acc.y += (float)((v3 >> 8) & 0xffu) * p3;
            acc.z += (float)((v3 >> 16) & 0xffu) * p3;
            acc.w += (float)(v3 >> 24) * p3;
            accb += (p0 + p1) + (p2 + p3);
        }
        for (; e < cnt; e++) {
            int s = sl[e];
            float p = pl[e * 4 + hh];
            unsigned v = *(const unsigned*)(hbase + (size_t)s * 256);
            acc.x += (float)(v & 0xffu) * p;
            acc.y += (float)((v >> 8) & 0xffu) * p;
            acc.z += (float)((v >> 16) & 0xffu) * p;
            acc.w += (float)(v >> 24) * p;
            accb += p;
        }
        // GCN gather: group hh handles edges {hh, hh+4, ...}, 2 in flight
        int e2 = hh;
        for (; e2 + 4 < cnt; e2 += 8) {
            int sa = sl[e2], sb = sl[e2 + 4];
            ushort4 va = *(const ushort4*)(h1 + (size_t)sa * HH + cidx);
            ushort4 vb = *(const ushort4*)(h1 + (size_t)sb * HH + cidx);
            accc.x += bf2f(va.x) + bf2f(vb.x);
            accc.y += bf2f(va.y) + bf2f(vb.y);
            accc.z += bf2f(va.z) + bf2f(vb.z);
            accc.w += bf2f(va.w) + bf2f(vb.w);
        }
        if (e2 < cnt) {
            int sa = sl[e2];
            ushort4 va = *(const ushort4*)(h1 + (size_t)sa * HH + cidx);
            accc.x += bf2f(va.x); accc.y += bf2f(va.y);
            accc.z += bf2f(va.z); accc.w += bf2f(va.w);
        }
    }
    // int8 bias correction: subtract 128 * sum(p*s) once
    float corr = 128.0f * accb;
    acc.x -= corr; acc.y -= corr; acc.z -= corr; acc.w -= corr;
    // GAT epilogue
#pragma unroll
    for (int h = 0; h < 4; h++) {
        float v = lsum[h];
        for (int off = 32; off >= 1; off >>= 1) v += __shfl_xor(v, off, 64);
        lsum[h] = v + psf[h];
    }
    float lt = (hh & 2) ? ((hh & 1) ? lsum[3] : lsum[2]) : ((hh & 1) ? lsum[1] : lsum[0]);
    float li = 1.0f / lt;
    float4 bv = *(const float4*)(bgat + lane * 4);
    ushort4 o;
    o.x = f2bf(fmaxf(acc.x * li + bv.x, 0.f));
    o.y = f2bf(fmaxf(acc.y * li + bv.y, 0.f));
    o.z = f2bf(fmaxf(acc.z * li + bv.z, 0.f));
    o.w = f2bf(fmaxf(acc.w * li + bv.w, 0.f));
    *(ushort4*)(outg + (size_t)wid * 256 + lane * 4) = o;
    // GCN epilogue
#pragma unroll
    for (int off = 16; off <= 32; off <<= 1) {
        accc.x += __shfl_xor(accc.x, off, 64);
        accc.y += __shfl_xor(accc.y, off, 64);
        accc.z += __shfl_xor(accc.z, off, 64);
        accc.w += __shfl_xor(accc.w, off, 64);
    }
    if (hh == 0) {
        ushort4 sv = *(const ushort4*)(h1 + (size_t)wid * HH + cidx);
        float4 bc = *(const float4*)(bgcn + cidx);
        ushort4 oc;
        oc.x = f2bf(fmaxf((accc.x + bf2f(sv.x)) * di + bc.x, 0.f));
        oc.y = f2bf(fmaxf((accc.y + bf2f(sv.y)) * di + bc.y, 0.f));
        oc.z = f2bf(fmaxf((accc.z + bf2f(sv.z)) * di + bc.z, 0.f));
        oc.w = f2bf(fmaxf((accc.w + bf2f(sv.w)) * di + bc.w, 0.f));
        *(ushort4*)(outc + (size_t)wid * HH + cidx) = oc;
    }
}

// ---------------------------------------------------------------------------
// Final aggregation: fused GCN2 + GAT2 over the interleaved pair buffer.
// ---------------------------------------------------------------------------
__global__ __launch_bounds__(256) void final_agg(const unsigned* __restrict__ hp,
                                                 const int* __restrict__ rs,
                                                 const unsigned short* __restrict__ col,
                                                 const float* __restrict__ dinv,
                                                 const float* __restrict__ s2s,
                                                 const float* __restrict__ s2d,
                                                 const float* __restrict__ bg2,
                                                 const float* __restrict__ bga2,
                                                 float* __restrict__ out) {
    int t = blockIdx.x * 256 + threadIdx.x;
    int node = t >> 4;
    int c = t & 15;
    float di = dinv[node];
    float sd = s2d[node];
    float es = s2s[node] + sd;
    es = (es >= 0.f) ? es : 0.2f * es;
    float psf = __expf(es);
    unsigned pvs = hp[(size_t)node * 16 + c];
    float accg = bf2f((unsigned short)pvs);
    float acca = bf2f((unsigned short)(pvs >> 16)) * psf;
    float lp = 0.f;
    int beg = rs[node], end = rs[node + 1];
    for (int j0 = beg; j0 < end; j0 += 16) {
        int cnt = min(16, end - j0);
        int sreg = 0;
        float pr = 0.f;
        if (c < cnt) {
            sreg = (int)col[j0 + c];
            float e = s2s[sreg] + sd;
            e = (e >= 0.f) ? e : 0.2f * e;
            pr = __expf(e);
            lp += pr;
        }
        for (int e = 0; e < cnt; e += 4) {
            int si[4];
            float pi[4];
#pragma unroll
            for (int u = 0; u < 4; u++) {
                si[u] = __shfl(sreg, (e + u) & 15, 16);
                pi[u] = __shfl(pr, (e + u) & 15, 16);
            }
            unsigned hv[4];
#pragma unroll
            for (int u = 0; u < 4; u++) hv[u] = hp[(size_t)si[u] * 16 + c];
#pragma unroll
            for (int u = 0; u < 4; u++) {
                if (e + u < cnt) {
                    accg += bf2f((unsigned short)hv[u]);
                    acca += bf2f((unsigned short)(hv[u] >> 16)) * pi[u];
                }
            }
        }
    }
    for (int off = 8; off >= 1; off >>= 1) lp += __shfl_xor(lp, off, 16);
    float l = lp + psf;
    out[(size_t)node * 32 + c] = accg * di + bg2[c];
    out[(size_t)node * 32 + 16 + c] = acca / l + bga2[c];
}

// ---------------------------------------------------------------------------
// Launch
// ---------------------------------------------------------------------------
extern "C" void kernel_launch(void* const* d_in, const int* in_sizes, int n_in,
                              void* d_out, int out_size, void* d_ws, size_t ws_size,
                              hipStream_t stream) {
    const float* x      = (const float*)d_in[0];
    const int*   ei     = (const int*)d_in[1];
    const float* Wg1    = (const float*)d_in[2];
    const float* bg1    = (const float*)d_in[3];
    const float* Wg2    = (const float*)d_in[4];
    const float* bg2    = (const float*)d_in[5];
    const float* Wgat1  = (const float*)d_in[6];
    const float* a_src1 = (const float*)d_in[7];
    const float* a_dst1 = (const float*)d_in[8];
    const float* bgat1  = (const float*)d_in[9];
    const float* Wgat2  = (const float*)d_in[10];
    const float* a_src2 = (const float*)d_in[11];
    const float* a_dst2 = (const float*)d_in[12];
    const float* bgat2  = (const float*)d_in[13];
    float* out = (float*)d_out;

    const int* e_src = ei;
    const int* e_dst = ei + EE;

    char* wsb = (char*)d_ws;
    size_t o = 0;
    auto alloc = [&](size_t bytes) -> void* {
        void* p = wsb + o;
        o += (bytes + 255) & ~(size_t)255;
        return p;
    };
    float* dinv            = (float*)alloc(NN * 4);
    float* ssrc1           = (float*)alloc((size_t)NN * 16);
    float* sdst1           = (float*)alloc((size_t)NN * 16);
    unsigned short* h1b    = (unsigned short*)alloc((size_t)NN * HH * 2);
    unsigned short* xg1    = (unsigned short*)alloc((size_t)NN * HH * 2);
    unsigned char*  hgb    = (unsigned char*)alloc((size_t)NN * 256);   // int8
    float* sclb            = (float*)alloc(NN * 4);                      // per-row scale
    unsigned short* xgat1  = (unsigned short*)alloc((size_t)NN * 256 * 2);
    unsigned short* pairb  = (unsigned short*)alloc((size_t)NN * 16 * 4);
    float* s2src           = (float*)alloc(NN * 4);
    float* s2dst           = (float*)alloc(NN * 4);
    unsigned short* bhiC   = (unsigned short*)alloc((size_t)8 * NTT * 512 * 2);
    unsigned short* bhiG2  = (unsigned short*)alloc(64 * 16 * 2);
    unsigned short* bloG2  = (unsigned short*)alloc(64 * 16 * 2);
    unsigned short* bhiA2  = (unsigned short*)alloc(256 * 16 * 2);
    unsigned short* bloA2  = (unsigned short*)alloc(256 * 16 * 2);
    int* cnt               = (int*)alloc(NN * 4);
    int* rowstart          = (int*)alloc((NN + 1) * 4);
    int* cursor            = (int*)alloc(NN * 4);
    unsigned short* colarr = (unsigned short*)alloc((size_t)EE * 2);

    const int TB = 256;
    const int NB = (NN + 255) / 256;
    const int GB = (NN + 63) / 64;    // 782 gemm blocks
    const int FB = (EE + 255) / 256;  // 3125 fill blocks
    const int SB = (NN * HH / 8 + 255) / 256;  // 1563 h1-scale blocks
    const int G16 = (NN * 16) / 256;  // 3125

    // weight packing + cnt zeroing
    k_prep<<<NB, TB, 0, stream>>>(Wg1, Wgat1, Wg2, Wgat2,
                                  bhiC, bhiG2, bloG2, bhiA2, bloA2, cnt);
    // big GEMM (h1 unscaled) with edge-count blocks interleaved 1:2
    gemm_count<<<3 * GB, 512, 0, stream>>>(x, bhiC, h1b, hgb, sclb,
                                           a_src1, a_dst1, ssrc1, sdst1,
                                           e_dst, cnt, NN);
    // single-kernel scan (round-12: was 3 launches)
    k_scan<<<NB, TB, 0, stream>>>(cnt, rowstart, cursor, dinv, NN);
    // CSR fill + h1 dinv-scaling, one launch
    fill_scale<<<FB + SB, TB, 0, stream>>>(e_src, e_dst, cursor, colarr,
                                           h1b, dinv, FB);

    both_agg<<<NN / 4, TB, 0, stream>>>(hgb, h1b, sclb, rowstart, colarr, ssrc1, sdst1,
                                        dinv, bgat1, bg1, xgat1, xg1);

    mfma_n16_both<<<2 * GB, TB, 0, stream>>>(xgat1, xg1, bhiA2, bloA2, bhiG2, bloG2,
                                             pairb, dinv, a_src2, a_dst2,
                                             s2src, s2dst, NN, GB);

    final_agg<<<G16, TB, 0, stream>>>((const unsigned*)pairb, rowstart, colarr, dinv,
                                      s2src, s2dst, bg2, bgat2, out);
}

// Round 14
// 309.621 us; speedup vs baseline: 1.0747x; 1.0646x over previous
//
#include <hip/hip_runtime.h>
#include <math.h>

#define NN     50000
#define FF     256
#define HH     64
#define NHEADS 4
#define EE     800000
#define OUTD   16

typedef __attribute__((ext_vector_type(8))) short short8;
typedef __attribute__((ext_vector_type(4))) float f32x4;

__device__ inline unsigned short f2bf(float f) {
    unsigned u = __builtin_bit_cast(unsigned, f);
    unsigned r = (u + 0x7fff + ((u >> 16) & 1)) >> 16;
    return (unsigned short)r;
}
__device__ inline float bf2f(unsigned short s) {
    unsigned u = ((unsigned)s) << 16;
    return __builtin_bit_cast(float, u);
}

// ---------------------------------------------------------------------------
// FINAL (round-14 consolidation = round-10 best-measured config, 313.5us).
// Ladder: 349.8 start -> int8 hg (fetch halved) -> 512-thr split GEMM ->
// B LDS-staged via global_load_lds -> k_count merged into GEMM launch +
// deferred h1 scaling. Clock noise +-6% now exceeds remaining levers.
// ---------------------------------------------------------------------------
__device__ inline void pack_one(const float* __restrict__ W,
                                unsigned short* __restrict__ bhi,
                                unsigned short* __restrict__ blo,
                                int t_, int NT, int NTOT, int TOFF, int SRC_NC) {
    int lane = t_ & 63;
    int tile = (t_ >> 6) % NT;
    int kb = (t_ >> 6) / NT;
    int q = lane >> 4, c = lane & 15;
    size_t off = ((size_t)(kb * NTOT + TOFF + tile) * 64 + lane) * 8;
#pragma unroll
    for (int j = 0; j < 8; j++) {
        float w = W[(size_t)(kb * 32 + q * 8 + j) * SRC_NC + tile * 16 + c];
        unsigned short h = f2bf(w);
        bhi[off + j] = h;
        if (blo) blo[off + j] = f2bf(w - bf2f(h));
    }
}

#define NTT 20
// zero cnt + pack all four weights, one launch (independent work).
__global__ __launch_bounds__(256) void k_prep(const float* __restrict__ Wg1,
                                              const float* __restrict__ Wgat1,
                                              const float* __restrict__ Wg2,
                                              const float* __restrict__ Wgat2,
                                              unsigned short* __restrict__ bhiC,
                                              unsigned short* __restrict__ bhiG2,
                                              unsigned short* __restrict__ bloG2,
                                              unsigned short* __restrict__ bhiA2,
                                              unsigned short* __restrict__ bloA2,
                                              int* __restrict__ cnt) {
    int t = blockIdx.x * 256 + threadIdx.x;
    if (t < NN) cnt[t] = 0;
    if (t < 2048)        pack_one(Wg1,   bhiC,  nullptr, t,         4,  NTT, 0, 64);
    else if (t < 10240)  pack_one(Wgat1, bhiC,  nullptr, t - 2048,  16, NTT, 4, 256);
    else if (t < 10368)  pack_one(Wg2,   bhiG2, bloG2,   t - 10240, 1,  1,   0, 16);
    else if (t < 10880)  pack_one(Wgat2, bhiA2, bloA2,   t - 10368, 1,  1,   0, 16);
}

__global__ __launch_bounds__(256) void k_scan_a(const int* __restrict__ cnt,
                                                int* __restrict__ partial, int n) {
    int i = blockIdx.x * 256 + threadIdx.x;
    int v = (i < n) ? cnt[i] : 0;
#pragma unroll
    for (int off = 32; off >= 1; off >>= 1) v += __shfl_xor(v, off, 64);
    __shared__ int ws[4];
    int wave = threadIdx.x >> 6;
    if ((threadIdx.x & 63) == 0) ws[wave] = v;
    __syncthreads();
    if (threadIdx.x == 0) partial[blockIdx.x] = ws[0] + ws[1] + ws[2] + ws[3];
}

__global__ __launch_bounds__(256) void k_scan_b(const int* __restrict__ partial,
                                                int* __restrict__ blockoff,
                                                int* __restrict__ total_out, int nb) {
    __shared__ int arr[256];
    int tid = threadIdx.x;
    arr[tid] = (tid < nb) ? partial[tid] : 0;
    __syncthreads();
#pragma unroll
    for (int off = 1; off < 256; off <<= 1) {
        int v = arr[tid];
        int add = (tid >= off) ? arr[tid - off] : 0;
        __syncthreads();
        arr[tid] = v + add;
        __syncthreads();
    }
    if (tid < nb) blockoff[tid] = arr[tid] - partial[tid];
    if (tid == 0) *total_out = arr[255];
}

__global__ __launch_bounds__(256) void k_scan_c(const int* __restrict__ cnt,
                                                const int* __restrict__ blockoff,
                                                int* __restrict__ row_start,
                                                int* __restrict__ cursor,
                                                float* __restrict__ dinv, int n) {
    __shared__ int arr[256];
    int tid = threadIdx.x;
    int i = blockIdx.x * 256 + tid;
    int c = (i < n) ? cnt[i] : 0;
    arr[tid] = c;
    __syncthreads();
#pragma unroll
    for (int off = 1; off < 256; off <<= 1) {
        int v = arr[tid];
        int add = (tid >= off) ? arr[tid - off] : 0;
        __syncthreads();
        arr[tid] = v + add;
        __syncthreads();
    }
    if (i < n) {
        int excl = arr[tid] - c + blockoff[blockIdx.x];
        row_start[i] = excl;
        cursor[i] = excl;
        dinv[i] = rsqrtf((float)(c + 1));
    }
}

// k_fill + h1 dinv-scale, one launch (independent block ranges).
__global__ __launch_bounds__(256) void fill_scale(const int* __restrict__ src,
                                                  const int* __restrict__ dst,
                                                  int* __restrict__ cursor,
                                                  int* __restrict__ col,
                                                  unsigned short* __restrict__ h1,
                                                  const float* __restrict__ dinv,
                                                  int FB) {
    int bx = blockIdx.x;
    if (bx < FB) {
        int i = bx * 256 + threadIdx.x;
        if (i < EE) {
            int d = dst[i];
            int pos = atomicAdd(&cursor[d], 1);
            col[pos] = src[i];
        }
    } else {
        int t = (bx - FB) * 256 + threadIdx.x;   // 8 bf16 per thread
        if (t < NN * HH / 8) {
            int r = t >> 3;
            float sc = dinv[r];
            short8 v = *(short8*)(h1 + (size_t)t * 8);
#pragma unroll
            for (int j = 0; j < 8; j++)
                v[j] = (short)f2bf(bf2f((unsigned short)v[j]) * sc);
            *(short8*)(h1 + (size_t)t * 8) = v;
        }
    }
}

// ---------------------------------------------------------------------------
// FUSED big GEMM (512-thr, 8 waves; waves 0-3 tiles 0-9, waves 4-7 tiles
// 10-19 of the same rows) + MERGED k_count blocks (tail). B staged once
// per block into LDS via global_load_lds, double-buffered. h1 written
// UNSCALED (dinv applied by fill_scale) so count has no dependency.
// ---------------------------------------------------------------------------
__global__ __launch_bounds__(512, 4) void gemm_count(const float* __restrict__ A,
                                                     const unsigned short* __restrict__ Bhi,
                                                     unsigned short* __restrict__ Ch1,
                                                     unsigned char* __restrict__ Chg,
                                                     float* __restrict__ scl,
                                                     const float* __restrict__ a_s,
                                                     const float* __restrict__ a_d,
                                                     float* __restrict__ ssrc,
                                                     float* __restrict__ sdst,
                                                     const int* __restrict__ e_dst,
                                                     int* __restrict__ cnt,
                                                     int M, int GBp) {
    if (blockIdx.x >= GBp) {
        int i = (blockIdx.x - GBp) * 512 + threadIdx.x;
        if (i < EE) atomicAdd(&cnt[e_dst[i]], 1);
        return;
    }
    const int K = 256;
    int tid = threadIdx.x;
    int w = tid >> 6, lane = tid & 63, q = lane >> 4, c = lane & 15;
    int rg = w & 3;          // row group within block (16 rows each)
    int half = w >> 2;       // tile half: 0 -> tiles 0..9, 1 -> tiles 10..19
    const int T0 = half * 10;
    int row_base = blockIdx.x * 64 + rg * 16;
    int ar = min(row_base + c, M - 1);
    const float* ap = A + (size_t)ar * K + q * 8;

    __shared__ unsigned short ldsB[2][NTT * 512];   // 2 x 20 KB

    auto stage = [&](int kb, int buf) {
        const char* srcb = (const char*)Bhi + (size_t)kb * (NTT * 1024);
#pragma unroll
        for (int cch = 0; cch < 3; cch++) {
            int ch = w + cch * 8;
            if (ch < NTT) {
                __builtin_amdgcn_global_load_lds(
                    (const unsigned int*)(srcb + ch * 1024 + lane * 16),
                    (unsigned int*)((char*)&ldsB[buf][0] + ch * 1024),
                    16, 0, 0);
            }
        }
    };

    f32x4 acc[10];
#pragma unroll
    for (int t = 0; t < 10; t++) acc[t] = (f32x4){0.f, 0.f, 0.f, 0.f};

    float av[8];
    *(float4*)(av)     = *(const float4*)(ap);
    *(float4*)(av + 4) = *(const float4*)(ap + 4);
    stage(0, 0);
    __syncthreads();

    int buf = 0;
#pragma unroll
    for (int kb = 0; kb < 8; kb++) {
        if (kb < 7) stage(kb + 1, buf ^ 1);
        short8 ahi, alo;
#pragma unroll
        for (int j = 0; j < 8; j++) {
            unsigned short h = f2bf(av[j]);
            ahi[j] = (short)h;
            alo[j] = (short)f2bf(av[j] - bf2f(h));
        }
        if (kb < 7) {
            *(float4*)(av)     = *(const float4*)(ap + (kb + 1) * 32);
            *(float4*)(av + 4) = *(const float4*)(ap + (kb + 1) * 32 + 4);
        }
        const char* bbase = (const char*)&ldsB[buf][0] + lane * 16;
#pragma unroll
        for (int lt = 0; lt < 10; lt++) {
            short8 b = *(const short8*)(bbase + (size_t)(T0 + lt) * 1024);
            acc[lt] = __builtin_amdgcn_mfma_f32_16x16x32_bf16(ahi, b, acc[lt], 0, 0, 0);
            acc[lt] = __builtin_amdgcn_mfma_f32_16x16x32_bf16(alo, b, acc[lt], 0, 0, 0);
        }
        __syncthreads();
        buf ^= 1;
    }

    __shared__ float s_ss[2][64][4];
    __shared__ float s_sd[2][64][4];
    __shared__ float s_mx[2][64];

#pragma unroll
    for (int i = 0; i < 4; i++) {
        int lr = rg * 16 + q * 4 + i;
        float ss[4] = {0.f, 0.f, 0.f, 0.f};
        float sd[4] = {0.f, 0.f, 0.f, 0.f};
        float m = 0.f;
#pragma unroll
        for (int lt = 0; lt < 10; lt++) {
            int gt = T0 + lt;
            if (gt >= 4) {
                int t = gt - 4;
                float v = acc[lt][i];
                ss[t >> 2] += v * a_s[t * 16 + c];
                sd[t >> 2] += v * a_d[t * 16 + c];
                m = fmaxf(m, fabsf(v));
            }
        }
#pragma unroll
        for (int h = 0; h < 4; h++) {
#pragma unroll
            for (int off = 1; off <= 8; off <<= 1) {
                ss[h] += __shfl_xor(ss[h], off, 16);
                sd[h] += __shfl_xor(sd[h], off, 16);
            }
        }
#pragma unroll
        for (int off = 1; off <= 8; off <<= 1) m = fmaxf(m, __shfl_xor(m, off, 16));
        if (c == i) {
#pragma unroll
            for (int h = 0; h < 4; h++) {
                s_ss[half][lr][h] = ss[h];
                s_sd[half][lr][h] = sd[h];
            }
            s_mx[half][lr] = m;
        }
    }
    __syncthreads();

#pragma unroll
    for (int i = 0; i < 4; i++) {
        int lr = rg * 16 + q * 4 + i;
        int r = row_base + q * 4 + i;
        float m = fmaxf(fmaxf(s_mx[0][lr], s_mx[1][lr]), 1e-20f);
        float inv = 127.0f / m;
        if (half == 0 && c == i && r < M) {
            *(float4*)(ssrc + (size_t)r * 4) =
                make_float4(s_ss[0][lr][0] + s_ss[1][lr][0], s_ss[0][lr][1] + s_ss[1][lr][1],
                            s_ss[0][lr][2] + s_ss[1][lr][2], s_ss[0][lr][3] + s_ss[1][lr][3]);
            *(float4*)(sdst + (size_t)r * 4) =
                make_float4(s_sd[0][lr][0] + s_sd[1][lr][0], s_sd[0][lr][1] + s_sd[1][lr][1],
                            s_sd[0][lr][2] + s_sd[1][lr][2], s_sd[0][lr][3] + s_sd[1][lr][3]);
            scl[r] = m * (1.0f / 127.0f);
        }
        if (r < M) {
            if (half == 0) {
#pragma unroll
                for (int lt = 0; lt < 4; lt++)
                    Ch1[(size_t)r * 64 + lt * 16 + c] = f2bf(acc[lt][i]);  // unscaled
            }
#pragma unroll
            for (int lt = 0; lt < 10; lt++) {
                int gt = T0 + lt;
                if (gt >= 4) {
                    int t = gt - 4;
                    int qv = (int)rintf(acc[lt][i] * inv) + 128;
                    Chg[(size_t)r * 256 + t * 16 + c] = (unsigned char)qv;
                }
            }
        }
    }
}

// ---------------------------------------------------------------------------
// N=16 MFMA GEMM body; both small GEMMs in one launch (block-range split).
// ---------------------------------------------------------------------------
template <int KB, bool SCALE, bool SC2, int OFS>
__device__ inline void n16_body(int bx, int tid,
                                const unsigned short* __restrict__ A,
                                const unsigned short* __restrict__ Bhi,
                                const unsigned short* __restrict__ Blo,
                                unsigned short* __restrict__ Cbf,
                                const float* __restrict__ rowscale,
                                const float* __restrict__ a_s2,
                                const float* __restrict__ a_d2,
                                float* __restrict__ s2s,
                                float* __restrict__ s2d, int M) {
    const int K = KB * 32;
    int w = tid >> 6, lane = tid & 63, q = lane >> 4, c = lane & 15;
    int row_base = bx * 64 + w * 16;
    int ar = min(row_base + c, M - 1);
    const unsigned short* ap = A + (size_t)ar * K + q * 8;
    f32x4 acc = (f32x4){0.f, 0.f, 0.f, 0.f};
#pragma unroll
    for (int kb = 0; kb < KB; kb++) {
        short8 av = *(const short8*)(ap + kb * 32);
        size_t bo = ((size_t)kb * 64 + lane) * 8;
        short8 bh = *(const short8*)(Bhi + bo);
        short8 bl = *(const short8*)(Blo + bo);
        acc = __builtin_amdgcn_mfma_f32_16x16x32_bf16(av, bh, acc, 0, 0, 0);
        acc = __builtin_amdgcn_mfma_f32_16x16x32_bf16(av, bl, acc, 0, 0, 0);
    }
    if (SC2) {
#pragma unroll
        for (int i = 0; i < 4; i++) {
            float ps = acc[i] * a_s2[c];
            float pd = acc[i] * a_d2[c];
#pragma unroll
            for (int off = 1; off <= 8; off <<= 1) {
                ps += __shfl_xor(ps, off, 16);
                pd += __shfl_xor(pd, off, 16);
            }
            int r = row_base + q * 4 + i;
            if (c == i && r < M) {
                s2s[r] = ps;
                s2d[r] = pd;
            }
        }
    }
#pragma unroll
    for (int i = 0; i < 4; i++) {
        int r = row_base + q * 4 + i;
        if (r < M) {
            float sc = SCALE ? rowscale[r] : 1.0f;
            Cbf[((size_t)r * 16 + c) * 2 + OFS] = f2bf(acc[i] * sc);
        }
    }
}

__global__ __launch_bounds__(256) void mfma_n16_both(const unsigned short* __restrict__ Ag,
                                                     const unsigned short* __restrict__ Ac,
                                                     const unsigned short* __restrict__ bhiA2,
                                                     const unsigned short* __restrict__ bloA2,
                                                     const unsigned short* __restrict__ bhiG2,
                                                     const unsigned short* __restrict__ bloG2,
                                                     unsigned short* __restrict__ pairb,
                                                     const float* __restrict__ dinv,
                                                     const float* __restrict__ a_s2,
                                                     const float* __restrict__ a_d2,
                                                     float* __restrict__ s2s,
                                                     float* __restrict__ s2d,
                                                     int M, int GB) {
    int bx = blockIdx.x;
    if (bx < GB)
        n16_body<8, false, true, 1>(bx, threadIdx.x, Ag, bhiA2, bloA2, pairb,
                                    nullptr, a_s2, a_d2, s2s, s2d, M);
    else
        n16_body<2, true, false, 0>(bx - GB, threadIdx.x, Ac, bhiG2, bloG2, pairb,
                                    dinv, nullptr, nullptr, nullptr, nullptr, M);
}

// ---------------------------------------------------------------------------
// FUSED layer-1 aggregation: GAT1 (LDS-staged p/src, UNROLL-4 gather) +
// GCN1 riding the same sl[]. GAT hidden gathered as biased int8
// (4 B/lane/edge); h1 bf16.
// ---------------------------------------------------------------------------
__global__ __launch_bounds__(256) void both_agg(const unsigned char* __restrict__ hg,
                                                const unsigned short* __restrict__ h1,
                                                const float* __restrict__ scl,
                                                const int* __restrict__ rs,
                                                const int* __restrict__ col,
                                                const float* __restrict__ ssrc,
                                                const float* __restrict__ sdst,
                                                const float* __restrict__ dinv,
                                                const float* __restrict__ bgat,
                                                const float* __restrict__ bgcn,
                                                unsigned short* __restrict__ outg,
                                                unsigned short* __restrict__ outc) {
    __shared__ int s_lds[4][64];
    __shared__ float p_lds[4][64 * 4];
    int tid = threadIdx.x;
    int w = tid >> 6, lane = tid & 63;
    int wid = blockIdx.x * 4 + w;       // grid exact: 12500*4 = NN
    int hh = lane >> 4;
    int cidx = (lane & 15) * 4;
    int* sl = s_lds[w];
    float* pl = p_lds[w];

    float di = dinv[wid];
    float4 sd4 = *(const float4*)(sdst + (size_t)wid * 4);
    float sdv[4] = {sd4.x, sd4.y, sd4.z, sd4.w};
    float4 sf4 = *(const float4*)(ssrc + (size_t)wid * 4);
    float sfv[4] = {sf4.x, sf4.y, sf4.z, sf4.w};
    float psf[4];
#pragma unroll
    for (int h = 0; h < 4; h++) {
        float e = sfv[h] + sdv[h];
        e = (e >= 0.f) ? e : 0.2f * e;
        psf[h] = __expf(e);
    }
    float pse = (hh & 2) ? ((hh & 1) ? psf[3] : psf[2]) : ((hh & 1) ? psf[1] : psf[0]);
    // self term: decode with explicit -128 (bias correction below covers edges only)
    float pses = pse * scl[wid];
    const unsigned char* hbase = hg + lane * 4;
    unsigned hv0 = *(const unsigned*)(hbase + (size_t)wid * 256);
    float4 acc;
    acc.x = ((float)(hv0 & 0xffu) - 128.f) * pses;
    acc.y = ((float)((hv0 >> 8) & 0xffu) - 128.f) * pses;
    acc.z = ((float)((hv0 >> 16) & 0xffu) - 128.f) * pses;
    acc.w = ((float)(hv0 >> 24) - 128.f) * pses;
    float accb = 0.f;   // sum of p*s over edges (for -128 bias correction)
    float4 accc = make_float4(0.f, 0.f, 0.f, 0.f);

    float lsum[4] = {0.f, 0.f, 0.f, 0.f};
    int beg = rs[wid], end = rs[wid + 1];
    for (int j0 = beg; j0 < end; j0 += 64) {
        int cnt = min(64, end - j0);
        if (lane < cnt) {
            int sreg = col[j0 + lane];
            float ssc = scl[sreg];
            float4 sv = *(const float4*)(ssrc + (size_t)sreg * 4);
            float svv[4] = {sv.x, sv.y, sv.z, sv.w};
            float pv[4];
#pragma unroll
            for (int h = 0; h < 4; h++) {
                float e = svv[h] + sdv[h];
                e = (e >= 0.f) ? e : 0.2f * e;
                pv[h] = __expf(e);
                lsum[h] += pv[h];
            }
            sl[lane] = sreg;
            *(float4*)&pl[lane * 4] =
                make_float4(pv[0] * ssc, pv[1] * ssc, pv[2] * ssc, pv[3] * ssc);
        }
        // same-wave LDS write->read: DS pipe in-order per wave, no barrier
        int e = 0;
        for (; e + 4 <= cnt; e += 4) {
            int s0 = sl[e], s1 = sl[e + 1], s2 = sl[e + 2], s3 = sl[e + 3];
            float p0 = pl[e * 4 + hh], p1 = pl[(e + 1) * 4 + hh];
            float p2 = pl[(e + 2) * 4 + hh], p3 = pl[(e + 3) * 4 + hh];
            unsigned v0 = *(const unsigned*)(hbase + (size_t)s0 * 256);
            unsigned v1 = *(const unsigned*)(hbase + (size_t)s1 * 256);
            unsigned v2 = *(const unsigned*)(hbase + (size_t)s2 * 256);
            unsigned v3 = *(const unsigned*)(hbase + (size_t)s3 * 256);
            acc.x += (float)(v0 & 0xffu) * p0;
            acc.y += (float)((v0 >> 8) & 0xffu) * p0;
            acc.z += (float)((v0 >> 16) & 0xffu) * p0;
            acc.w += (float)(v0 >> 24) * p0;
            acc.x += (float)(v1 & 0xffu) * p1;
            acc.y += (float)((v1 >> 8) & 0xffu) * p1;
            acc.z += (float)((v1 >> 16) & 0xffu) * p1;
            acc.w += (float)(v1 >> 24) * p1;
            acc.x += (float)(v2 & 0xffu) * p2;
            acc.y += (float)((v2 >> 8) & 0xffu) * p2;
            acc.z += (float)((v2 >> 16) & 0xffu) * p2;
            acc.w += (float)(v2 >> 24) * p2;
            acc.x += (float)(v3 & 0xffu) * p3;
            acc.y += (float)((v3 >> 8) & 0xffu) * p3;
            acc.z += (float)((v3 >> 16) & 0xffu) * p3;
            acc.w += (float)(v3 >> 24) * p3;
            accb += (p0 + p1) + (p2 + p3);
        }
        for (; e < cnt; e++) {
            int s = sl[e];
            float p = pl[e * 4 + hh];
            unsigned v = *(const unsigned*)(hbase + (size_t)s * 256);
            acc.x += (float)(v & 0xffu) * p;
            acc.y += (float)((v >> 8) & 0xffu) * p;
            acc.z += (float)((v >> 16) & 0xffu) * p;
            acc.w += (float)(v >> 24) * p;
            accb += p;
        }
        // GCN gather: group hh handles edges {hh, hh+4, ...}, 2 in flight
        int e2 = hh;
        for (; e2 + 4 < cnt; e2 += 8) {
            int sa = sl[e2], sb = sl[e2 + 4];
            ushort4 va = *(const ushort4*)(h1 + (size_t)sa * HH + cidx);
            ushort4 vb = *(const ushort4*)(h1 + (size_t)sb * HH + cidx);
            accc.x += bf2f(va.x) + bf2f(vb.x);
            accc.y += bf2f(va.y) + bf2f(vb.y);
            accc.z += bf2f(va.z) + bf2f(vb.z);
            accc.w += bf2f(va.w) + bf2f(vb.w);
        }
        if (e2 < cnt) {
            int sa = sl[e2];
            ushort4 va = *(const ushort4*)(h1 + (size_t)sa * HH + cidx);
            accc.x += bf2f(va.x); accc.y += bf2f(va.y);
            accc.z += bf2f(va.z); accc.w += bf2f(va.w);
        }
    }
    // int8 bias correction: subtract 128 * sum(p*s) once
    float corr = 128.0f * accb;
    acc.x -= corr; acc.y -= corr; acc.z -= corr; acc.w -= corr;
    // GAT epilogue
#pragma unroll
    for (int h = 0; h < 4; h++) {
        float v = lsum[h];
        for (int off = 32; off >= 1; off >>= 1) v += __shfl_xor(v, off, 64);
        lsum[h] = v + psf[h];
    }
    float lt = (hh & 2) ? ((hh & 1) ? lsum[3] : lsum[2]) : ((hh & 1) ? lsum[1] : lsum[0]);
    float li = 1.0f / lt;
    float4 bv = *(const float4*)(bgat + lane * 4);
    ushort4 o;
    o.x = f2bf(fmaxf(acc.x * li + bv.x, 0.f));
    o.y = f2bf(fmaxf(acc.y * li + bv.y, 0.f));
    o.z = f2bf(fmaxf(acc.z * li + bv.z, 0.f));
    o.w = f2bf(fmaxf(acc.w * li + bv.w, 0.f));
    *(ushort4*)(outg + (size_t)wid * 256 + lane * 4) = o;
    // GCN epilogue
#pragma unroll
    for (int off = 16; off <= 32; off <<= 1) {
        accc.x += __shfl_xor(accc.x, off, 64);
        accc.y += __shfl_xor(accc.y, off, 64);
        accc.z += __shfl_xor(accc.z, off, 64);
        accc.w += __shfl_xor(accc.w, off, 64);
    }
    if (hh == 0) {
        ushort4 sv = *(const ushort4*)(h1 + (size_t)wid * HH + cidx);
        float4 bc = *(const float4*)(bgcn + cidx);
        ushort4 oc;
        oc.x = f2bf(fmaxf((accc.x + bf2f(sv.x)) * di + bc.x, 0.f));
        oc.y = f2bf(fmaxf((accc.y + bf2f(sv.y)) * di + bc.y, 0.f));
        oc.z = f2bf(fmaxf((accc.z + bf2f(sv.z)) * di + bc.z, 0.f));
        oc.w = f2bf(fmaxf((accc.w + bf2f(sv.w)) * di + bc.w, 0.f));
        *(ushort4*)(outc + (size_t)wid * HH + cidx) = oc;
    }
}

// ---------------------------------------------------------------------------
// Final aggregation: fused GCN2 + GAT2 over the interleaved pair buffer.
// ---------------------------------------------------------------------------
__global__ __launch_bounds__(256) void final_agg(const unsigned* __restrict__ hp,
                                                 const int* __restrict__ rs,
                                                 const int* __restrict__ col,
                                                 const float* __restrict__ dinv,
                                                 const float* __restrict__ s2s,
                                                 const float* __restrict__ s2d,
                                                 const float* __restrict__ bg2,
                                                 const float* __restrict__ bga2,
                                                 float* __restrict__ out) {
    int t = blockIdx.x * 256 + threadIdx.x;
    int node = t >> 4;
    int c = t & 15;
    float di = dinv[node];
    float sd = s2d[node];
    float es = s2s[node] + sd;
    es = (es >= 0.f) ? es : 0.2f * es;
    float psf = __expf(es);
    unsigned pvs = hp[(size_t)node * 16 + c];
    float accg = bf2f((unsigned short)pvs);
    float acca = bf2f((unsigned short)(pvs >> 16)) * psf;
    float lp = 0.f;
    int beg = rs[node], end = rs[node + 1];
    for (int j0 = beg; j0 < end; j0 += 16) {
        int cnt = min(16, end - j0);
        int sreg = 0;
        float pr = 0.f;
        if (c < cnt) {
            sreg = col[j0 + c];
            float e = s2s[sreg] + sd;
            e = (e >= 0.f) ? e : 0.2f * e;
            pr = __expf(e);
            lp += pr;
        }
        for (int e = 0; e < cnt; e += 4) {
            int si[4];
            float pi[4];
#pragma unroll
            for (int u = 0; u < 4; u++) {
                si[u] = __shfl(sreg, (e + u) & 15, 16);
                pi[u] = __shfl(pr, (e + u) & 15, 16);
            }
            unsigned hv[4];
#pragma unroll
            for (int u = 0; u < 4; u++) hv[u] = hp[(size_t)si[u] * 16 + c];
#pragma unroll
            for (int u = 0; u < 4; u++) {
                if (e + u < cnt) {
                    accg += bf2f((unsigned short)hv[u]);
                    acca += bf2f((unsigned short)(hv[u] >> 16)) * pi[u];
                }
            }
        }
    }
    for (int off = 8; off >= 1; off >>= 1) lp += __shfl_xor(lp, off, 16);
    float l = lp + psf;
    out[(size_t)node * 32 + c] = accg * di + bg2[c];
    out[(size_t)node * 32 + 16 + c] = acca / l + bga2[c];
}

// ---------------------------------------------------------------------------
// Launch
// ---------------------------------------------------------------------------
extern "C" void kernel_launch(void* const* d_in, const int* in_sizes, int n_in,
                              void* d_out, int out_size, void* d_ws, size_t ws_size,
                              hipStream_t stream) {
    const float* x      = (const float*)d_in[0];
    const int*   ei     = (const int*)d_in[1];
    const float* Wg1    = (const float*)d_in[2];
    const float* bg1    = (const float*)d_in[3];
    const float* Wg2    = (const float*)d_in[4];
    const float* bg2    = (const float*)d_in[5];
    const float* Wgat1  = (const float*)d_in[6];
    const float* a_src1 = (const float*)d_in[7];
    const float* a_dst1 = (const float*)d_in[8];
    const float* bgat1  = (const float*)d_in[9];
    const float* Wgat2  = (const float*)d_in[10];
    const float* a_src2 = (const float*)d_in[11];
    const float* a_dst2 = (const float*)d_in[12];
    const float* bgat2  = (const float*)d_in[13];
    float* out = (float*)d_out;

    const int* e_src = ei;
    const int* e_dst = ei + EE;

    char* wsb = (char*)d_ws;
    size_t o = 0;
    auto alloc = [&](size_t bytes) -> void* {
        void* p = wsb + o;
        o += (bytes + 255) & ~(size_t)255;
        return p;
    };
    float* dinv            = (float*)alloc(NN * 4);
    float* ssrc1           = (float*)alloc((size_t)NN * 16);
    float* sdst1           = (float*)alloc((size_t)NN * 16);
    unsigned short* h1b    = (unsigned short*)alloc((size_t)NN * HH * 2);
    unsigned short* xg1    = (unsigned short*)alloc((size_t)NN * HH * 2);
    unsigned char*  hgb    = (unsigned char*)alloc((size_t)NN * 256);   // int8
    float* sclb            = (float*)alloc(NN * 4);                      // per-row scale
    unsigned short* xgat1  = (unsigned short*)alloc((size_t)NN * 256 * 2);
    unsigned short* pairb  = (unsigned short*)alloc((size_t)NN * 16 * 4);
    float* s2src           = (float*)alloc(NN * 4);
    float* s2dst           = (float*)alloc(NN * 4);
    unsigned short* bhiC   = (unsigned short*)alloc((size_t)8 * NTT * 512 * 2);
    unsigned short* bhiG2  = (unsigned short*)alloc(64 * 16 * 2);
    unsigned short* bloG2  = (unsigned short*)alloc(64 * 16 * 2);
    unsigned short* bhiA2  = (unsigned short*)alloc(256 * 16 * 2);
    unsigned short* bloA2  = (unsigned short*)alloc(256 * 16 * 2);
    int* cnt               = (int*)alloc(NN * 4);
    int* rowstart          = (int*)alloc((NN + 1) * 4);
    int* cursor            = (int*)alloc(NN * 4);
    int* colarr            = (int*)alloc((size_t)EE * 4);
    int* partial           = (int*)alloc(256 * 4);
    int* blockoff          = (int*)alloc(256 * 4);

    const int TB = 256;
    const int NB = (NN + 255) / 256;
    const int GB = (NN + 63) / 64;    // 782 gemm blocks
    const int CB = (EE + 511) / 512;  // 1563 count blocks
    const int FB = (EE + 255) / 256;  // 3125 fill blocks
    const int SB = (NN * HH / 8 + 255) / 256;  // 1563 h1-scale blocks
    const int G16 = (NN * 16) / 256;  // 3125

    // weight packing + cnt zeroing
    k_prep<<<NB, TB, 0, stream>>>(Wg1, Wgat1, Wg2, Wgat2,
                                  bhiC, bhiG2, bloG2, bhiA2, bloA2, cnt);
    // big GEMM (h1 unscaled) with edge-count blocks hidden under it
    gemm_count<<<GB + CB, 512, 0, stream>>>(x, bhiC, h1b, hgb, sclb,
                                            a_src1, a_dst1, ssrc1, sdst1,
                                            e_dst, cnt, NN, GB);
    k_scan_a<<<NB, TB, 0, stream>>>(cnt, partial, NN);
    k_scan_b<<<1, TB, 0, stream>>>(partial, blockoff, rowstart + NN, NB);
    k_scan_c<<<NB, TB, 0, stream>>>(cnt, blockoff, rowstart, cursor, dinv, NN);
    // CSR fill + h1 dinv-scaling, one launch
    fill_scale<<<FB + SB, TB, 0, stream>>>(e_src, e_dst, cursor, colarr,
                                           h1b, dinv, FB);

    both_agg<<<NN / 4, TB, 0, stream>>>(hgb, h1b, sclb, rowstart, colarr, ssrc1, sdst1,
                                        dinv, bgat1, bg1, xgat1, xg1);

    mfma_n16_both<<<2 * GB, TB, 0, stream>>>(xgat1, xg1, bhiA2, bloA2, bhiG2, bloG2,
                                             pairb, dinv, a_src2, a_dst2,
                                             s2src, s2dst, NN, GB);

    final_agg<<<G16, TB, 0, stream>>>((const unsigned*)pairb, rowstart, colarr, dinv,
                                      s2src, s2dst, bg2, bgat2, out);
}